// Round 1
// baseline (184.439 us; speedup 1.0000x reference)
//
#include <hip/hip_runtime.h>
#include <hip/hip_bf16.h>

// BLAST factorized linear:
//   T[n, j*128+r] = sum_s X[n, j*256+s] * Vt[j,s,r]          (MFMA, per j)
//   u[o, n, r]    = sum_j S[o,j,r] * T[n, j*128+r]           (VALU fp32)
//   out[n,o*256+p]= bias[o*256+p] + sum_r u[o,n,r]*U[o,r,p]  (MFMA)
// One fused kernel, 16 rows per workgroup, T kept in LDS (bf16, swizzled).

typedef __bf16 bf16x8 __attribute__((ext_vector_type(8)));
typedef __bf16 bf16x4 __attribute__((ext_vector_type(4)));
typedef float  f32x4  __attribute__((ext_vector_type(4)));

#define IN_DIM  4096
#define OUT_DIM 4096
#define NROWS   8192
#define BJ      16
#define BO      16
#define BS_IN   256
#define BS_OUT  256
#define RANK    128

// --- LDS swizzle helpers: XOR the 8-element (16B) slot index with the row ---
__device__ __forceinline__ int swzT(int n, int c) {   // T_lds [16][2048]
  return n * 2048 + ((((c >> 3) ^ n) << 3) | (c & 7));
}
__device__ __forceinline__ int swzX(int n, int s) {   // X_lds [16][256]
  return n * 256 + ((((s >> 3) ^ n) << 3) | (s & 7));
}
__device__ __forceinline__ int swzU(int n, int r) {   // u_lds [16][128]
  return n * 128 + ((((r >> 3) ^ n) << 3) | (r & 7));
}

// prep: Vt (16,256,128) fp32 -> vt_t[j][r][s] bf16 ; U (16,128,256) fp32 -> u_t[o][p][r] bf16
__global__ __launch_bounds__(256) void prep_kernel(
    const float* __restrict__ Vt, const float* __restrict__ U,
    __bf16* __restrict__ vt_t, __bf16* __restrict__ u_t)
{
  const int NV = BJ * RANK * BS_IN;   // 524288
  const int NU = BO * BS_OUT * RANK;  // 524288
  int idx = blockIdx.x * 256 + threadIdx.x;
  if (idx < NV) {
    int j = idx >> 15;              // /(128*256)
    int r = (idx >> 8) & (RANK - 1);
    int s = idx & (BS_IN - 1);
    vt_t[idx] = (__bf16)Vt[(j * BS_IN + s) * RANK + r];
  } else {
    int k = idx - NV;
    if (k < NU) {
      int o = k >> 15;              // /(256*128)
      int p = (k >> 7) & (BS_OUT - 1);
      int r = k & (RANK - 1);
      u_t[k] = (__bf16)U[(o * RANK + r) * BS_OUT + p];
    }
  }
}

__global__ __launch_bounds__(256, 2) void blast_main(
    const float* __restrict__ x, const float* __restrict__ S,
    const float* __restrict__ bias,
    const __bf16* __restrict__ vt_t, const __bf16* __restrict__ u_t,
    float* __restrict__ out)
{
  __shared__ __bf16 T_lds[16 * 2048];  // 64 KB
  __shared__ __bf16 X_lds[16 * 256];   // 8 KB
  __shared__ __bf16 u_lds[16 * 128];   // 4 KB

  const int tid  = threadIdx.x;
  const int lane = tid & 63;
  const int w    = tid >> 6;       // wave 0..3
  const int l15  = lane & 15;
  const int lhi  = lane >> 4;
  const size_t rowbase = (size_t)blockIdx.x * 16;

  // ---------------- Stage A: T_lds[n][j*128+r] = X_j @ Vt_j ----------------
  for (int j = 0; j < BJ; ++j) {
    {
      const int n  = tid >> 4;           // 0..15
      const int s0 = (tid & 15) * 4;     // 0..60
      const float* xp = x + (rowbase + n) * IN_DIM + j * BS_IN;
      #pragma unroll
      for (int i = 0; i < 4; ++i) {
        const int s = s0 + 64 * i;
        const f32x4 v = *(const f32x4*)(xp + s);
        bf16x4 b;
        b[0] = (__bf16)v[0]; b[1] = (__bf16)v[1];
        b[2] = (__bf16)v[2]; b[3] = (__bf16)v[3];
        *(bf16x4*)&X_lds[swzX(n, s)] = b;
      }
    }
    __syncthreads();

    f32x4 acc0 = {0.f, 0.f, 0.f, 0.f};
    f32x4 acc1 = {0.f, 0.f, 0.f, 0.f};
    #pragma unroll
    for (int ks = 0; ks < 8; ++ks) {          // K = 256 = 8*32
      const bf16x8 a = *(const bf16x8*)&X_lds[swzX(l15, ks * 32 + lhi * 8)];
      const int r0 = w * 32 + l15;
      const bf16x8 b0 = *(const bf16x8*)&vt_t[(size_t)(j * RANK + r0) * BS_IN + ks * 32 + lhi * 8];
      const bf16x8 b1 = *(const bf16x8*)&vt_t[(size_t)(j * RANK + r0 + 16) * BS_IN + ks * 32 + lhi * 8];
      acc0 = __builtin_amdgcn_mfma_f32_16x16x32_bf16(a, b0, acc0, 0, 0, 0);
      acc1 = __builtin_amdgcn_mfma_f32_16x16x32_bf16(a, b1, acc1, 0, 0, 0);
    }
    // D layout: col = lane&15 (r), row = (lane>>4)*4 + v (n)
    #pragma unroll
    for (int v = 0; v < 4; ++v) {
      const int n = lhi * 4 + v;
      T_lds[swzT(n, j * RANK + w * 32 + l15)]      = (__bf16)acc0[v];
      T_lds[swzT(n, j * RANK + w * 32 + 16 + l15)] = (__bf16)acc1[v];
    }
    __syncthreads();
  }

  // ---------------- Stage B: per output block o ----------------
  for (int o = 0; o < BO; ++o) {
    // S-contraction: u[n][r] = sum_j S[o][j][r] * T[n][j*128+r]
    {
      const int n  = tid & 15;
      const int r0 = (tid >> 4) * 8;     // 0..120
      float u0=0,u1=0,u2=0,u3=0,u4=0,u5=0,u6=0,u7=0;
      #pragma unroll
      for (int j = 0; j < BJ; ++j) {
        const bf16x8 tv = *(const bf16x8*)&T_lds[swzT(n, j * RANK + r0)];
        const float* sp = S + (size_t)(o * BJ + j) * RANK + r0;
        const f32x4 s0 = *(const f32x4*)sp;
        const f32x4 s1 = *(const f32x4*)(sp + 4);
        u0 += s0[0] * (float)tv[0]; u1 += s0[1] * (float)tv[1];
        u2 += s0[2] * (float)tv[2]; u3 += s0[3] * (float)tv[3];
        u4 += s1[0] * (float)tv[4]; u5 += s1[1] * (float)tv[5];
        u6 += s1[2] * (float)tv[6]; u7 += s1[3] * (float)tv[7];
      }
      bf16x8 ub;
      ub[0] = (__bf16)u0; ub[1] = (__bf16)u1; ub[2] = (__bf16)u2; ub[3] = (__bf16)u3;
      ub[4] = (__bf16)u4; ub[5] = (__bf16)u5; ub[6] = (__bf16)u6; ub[7] = (__bf16)u7;
      *(bf16x8*)&u_lds[swzU(n, r0)] = ub;
    }
    __syncthreads();

    // out tile [16][256] = u @ U_o : wave w covers cols w*64..w*64+63
    f32x4 acc[4] = {{0.f,0.f,0.f,0.f},{0.f,0.f,0.f,0.f},{0.f,0.f,0.f,0.f},{0.f,0.f,0.f,0.f}};
    #pragma unroll
    for (int ks = 0; ks < 4; ++ks) {          // K = 128 = 4*32
      const bf16x8 a = *(const bf16x8*)&u_lds[swzU(l15, ks * 32 + lhi * 8)];
      #pragma unroll
      for (int cf = 0; cf < 4; ++cf) {
        const int p = w * 64 + cf * 16 + l15;
        const bf16x8 b = *(const bf16x8*)&u_t[(size_t)(o * BS_OUT + p) * RANK + ks * 32 + lhi * 8];
        acc[cf] = __builtin_amdgcn_mfma_f32_16x16x32_bf16(a, b, acc[cf], 0, 0, 0);
      }
    }
    #pragma unroll
    for (int cf = 0; cf < 4; ++cf) {
      const int col = o * BS_OUT + w * 64 + cf * 16 + l15;
      const float bv = bias[col];
      #pragma unroll
      for (int v = 0; v < 4; ++v) {
        out[(rowbase + lhi * 4 + v) * OUT_DIM + col] = acc[cf][v] + bv;
      }
    }
    __syncthreads();   // u_lds reused next o
  }
}

extern "C" void kernel_launch(void* const* d_in, const int* in_sizes, int n_in,
                              void* d_out, int out_size, void* d_ws, size_t ws_size,
                              hipStream_t stream) {
  const float* x    = (const float*)d_in[0];
  const float* S    = (const float*)d_in[1];
  const float* U    = (const float*)d_in[2];
  const float* Vt   = (const float*)d_in[3];
  const float* bias = (const float*)d_in[4];
  float* out = (float*)d_out;

  __bf16* vt_t = (__bf16*)d_ws;                    // 1 MB
  __bf16* u_t  = vt_t + (size_t)BJ * RANK * BS_IN; // 1 MB

  const int prep_elems = BJ * RANK * BS_IN + BO * BS_OUT * RANK; // 1048576
  prep_kernel<<<prep_elems / 256, 256, 0, stream>>>(Vt, U, vt_t, u_t);
  blast_main<<<NROWS / 16, 256, 0, stream>>>(x, S, bias, vt_t, u_t, out);
}